// Round 12
// baseline (133.793 us; speedup 1.0000x reference)
//
#include <hip/hip_runtime.h>
#include <math.h>

// Problem constants (reference: N=16384, D=128, T=0.07)
#define NROWS 16384
#define DDIM  128
constexpr float TEMP = 0.07f;
// Pre-scale trick: x *= sqrt(log2(e)/T) so MFMA emits acc = S*<xi,xj> and
// row_lse = ln(sum exp2(acc)). Diagonal (sim_ii = 1 exactly) is masked out
// of the fp8 path and added analytically (2^S) in finalize (R11-validated:
// absmax 0.0; off-diag is ~2.3% of rowsum so fp8 error is damped ~44x).
constexpr float S_EXP = 1.44269504088896f / TEMP;  // 20.6099291

typedef __attribute__((ext_vector_type(4))) float f32x4;

// ---------------------------------------------------------------------------
// FRAGMENT-ORDER fp8 array xbF (2 MB, L2-resident): byte for (row j, k) at
//   xbF[(j>>4)*2048 + (k>>5)*512 + ((k>>3)&3)*128 + (j&15)*8 + (k&7)]
// A 16x16x32 fp8 MFMA A/B fragment (lane: l15 = m-or-n, q = k-group) is then
// ONE lane-contiguous 512-B wave load -> no LDS, no barriers, no gathers.
// This kills the per-tile __syncthreads convoy that capped R7-R11 at ~51-64us
// (MfmaUtil+VALUBusy ~66% with ~34% barrier dead time across 4 structural
// A/Bs: dbuf@2blk / single@4blk / 2x-barriers / fp8-dbuf@4blk).
// ---------------------------------------------------------------------------

// Convert + pre-scale fp32 -> fp8 e4m3 (OCP, via v_cvt_pk_fp8_f32) directly
// into fragment order. Block b owns j16=b (16 rows x 128 k = one 2 KB cell);
// thread t reads 8 consecutive floats (coalesced), writes 8 B (coalesced).
__global__ void convert_k(const float* __restrict__ x, unsigned char* __restrict__ xbF,
                          float* __restrict__ accum, int* __restrict__ cnt) {
  const float R = 4.53981419f;  // sqrt(S_EXP); |x*R| <= ~1.3, inside e4m3 range
  const int b = blockIdx.x, t = threadIdx.x;
  const float* src = x + (size_t)b * 2048 + t * 8;  // row b*16+(t>>4), k0=(t&15)*8
  float4 v0 = *(const float4*)src;
  float4 v1 = *(const float4*)(src + 4);
  int p0 = __builtin_amdgcn_cvt_pk_fp8_f32(v0.x * R, v0.y * R, 0, false);
  p0 = __builtin_amdgcn_cvt_pk_fp8_f32(v0.z * R, v0.w * R, p0, true);
  int p1 = __builtin_amdgcn_cvt_pk_fp8_f32(v1.x * R, v1.y * R, 0, false);
  p1 = __builtin_amdgcn_cvt_pk_fp8_f32(v1.z * R, v1.w * R, p1, true);
  int2 pk = {p0, p1};
  // dest: kt=(t&15)>>2, q=t&3, l15=t>>4
  *(int2*)(xbF + (size_t)b * 2048 + (size_t)((t & 15) >> 2) * 512 +
           (t & 3) * 128 + (t >> 4) * 8) = pk;
  if (b == 0 && t == 0) { *accum = 0.f; *cnt = 0; }
}

// One 128x16 tile-slice: wave w computes ALL 128 rows of the I-block against
// its 16 cols of the J-block. Col-sum completes IN-WAVE (shuffle over q) ->
// plain 64-B store. Row-sums accumulate in rs[8][4] across tiles.
template <bool DZ>
__device__ __forceinline__ void tile_step(
    const unsigned char* __restrict__ xbF, const long (&af)[8][4],
    float (&rs)[8][4], float* __restrict__ colpart,
    int I, int d, int w, int q, int l15, int laneoff, bool qm, int dr) {
  const int J = (I + d) & 127;
  const unsigned char* gB = xbF + ((size_t)(J * 8 + w) << 11) + laneoff;
  long bfr[4];
#pragma unroll
  for (int kt = 0; kt < 4; ++kt) bfr[kt] = *(const long*)(gB + (kt << 9));
  float csl = 0.f;
#pragma unroll
  for (int rt = 0; rt < 8; ++rt) {
    f32x4 a = {0.f, 0.f, 0.f, 0.f};
#pragma unroll
    for (int kt = 0; kt < 4; ++kt)
      a = __builtin_amdgcn_mfma_f32_16x16x32_fp8_fp8(af[rt][kt], bfr[kt], a, 0, 0, 0);
    // C/D layout: col = l15, row = q*4 + r (within rt-tile of 16 rows)
#pragma unroll
    for (int r = 0; r < 4; ++r) {
      float e = __builtin_amdgcn_exp2f(a[r]);
      if (DZ) { if (rt == w && qm && r == dr) e = 0.f; }  // mask diagonal
      rs[rt][r] += e;
      csl += e;
    }
  }
  // col-sum over the tile's 128 rows: reduce over q -> complete in all lanes
  csl += __shfl_xor(csl, 16, 64);
  csl += __shfl_xor(csl, 32, 64);
  if (!DZ && d != 64 && q == 0)
    colpart[(size_t)(d - 1) * NROWS + (size_t)J * 128 + w * 16 + l15] = csl;
}

// Triangular Gram, BARRIER-FREE main loop. Block (I,s): d-tiles s==0: d=0..8
// else 8s+1..8s+8 (union 0..64 once per I; d=0 diag-masked, d=0/64 col-skip
// -- enumeration proven R5-R11). Wave w owns cols w*16..w*16+15 of every
// tile; A-frags (all 128 I-rows, 64 VGPRs) loaded once from xbF; B-frags
// one dwordx2 per kt from L2. Zero LDS staging; only 2 end-of-kernel
// barriers for the cross-wave row combine. R8 lesson: min-waves stays <=3
// (persistent regs = af 64 + rs 32; forcing 4 waves/EU risks spill).
__global__ __launch_bounds__(512, 3)
void gram_tri_k(const unsigned char* __restrict__ xbF, float* __restrict__ rowpart,
                float* __restrict__ colpart) {
  __shared__ float csbuf[8 * 128];  // 4 KB, end-combine only
  const int tid = threadIdx.x;
  const int w = tid >> 6, lane = tid & 63;
  const int l15 = lane & 15, q = lane >> 4;
  const int I = (int)(blockIdx.x >> 3), s = (int)(blockIdx.x & 7);
  const int dstart = (s == 0) ? 0 : 8 * s + 1;
  const int dend = (s == 0) ? 9 : 8 * s + 9;
  const int laneoff = q * 128 + l15 * 8;
  const bool qm = (l15 >> 2) == q;  // diagonal helpers (d==0 tile only)
  const int dr = l15 & 3;

  // A frags: rows rI + rt*16 + l15, k = kt*32 + q*8 .. +7 (fragment-order,
  // lane-contiguous 512-B wave loads; same cell layout as B).
  long af[8][4];
  const unsigned char* gA = xbF + ((size_t)(I * 8) << 11) + laneoff;
#pragma unroll
  for (int rt = 0; rt < 8; ++rt)
#pragma unroll
    for (int kt = 0; kt < 4; ++kt)
      af[rt][kt] = *(const long*)(gA + (rt << 11) + (kt << 9));

  float rs[8][4];
#pragma unroll
  for (int rt = 0; rt < 8; ++rt)
#pragma unroll
    for (int r = 0; r < 4; ++r) rs[rt][r] = 0.f;

  int d = dstart;
  if (s == 0) {  // d==0: diagonal-masked tile, no col store
    tile_step<true>(xbF, af, rs, colpart, I, d, w, q, l15, laneoff, qm, dr);
    ++d;
  }
  for (; d < dend; ++d)
    tile_step<false>(xbF, af, rs, colpart, I, d, w, q, l15, laneoff, qm, dr);

  // rows: reduce over the wave's 16 cols (l15) ...
#pragma unroll
  for (int m = 1; m <= 8; m <<= 1)
#pragma unroll
    for (int rt = 0; rt < 8; ++rt)
#pragma unroll
      for (int r = 0; r < 4; ++r)
        rs[rt][r] += __shfl_xor(rs[rt][r], m, 64);
  // ... then combine the 8 waves' 16-col slices via csbuf (only barriers!)
  if (l15 == 0) {
#pragma unroll
    for (int rt = 0; rt < 8; ++rt)
#pragma unroll
      for (int r = 0; r < 4; ++r)
        csbuf[w * 128 + rt * 16 + q * 4 + r] = rs[rt][r];
  }
  __syncthreads();
  if (tid < 128) {
    float v = 0.f;
#pragma unroll
    for (int w2 = 0; w2 < 8; ++w2) v += csbuf[w2 * 128 + tid];
    rowpart[(size_t)s * NROWS + (size_t)I * 128 + tid] = v;
  }
}

// 256 blocks x 64 threads, 1 row/thread (coalesced): sums 8 rowpart +
// 63 colpart slices, adds analytic diagonal 2^S, logs, wave-reduces.
__global__ void finalize_k(const float* __restrict__ rowpart, const float* __restrict__ colpart,
                           float* __restrict__ accum, int* __restrict__ cnt,
                           float* __restrict__ out) {
  const int tid = threadIdx.x;
  const size_t i = (size_t)blockIdx.x * 64 + tid;
  float v = __builtin_exp2f(S_EXP);  // exact diagonal term (rows unit-norm)
#pragma unroll
  for (int s2 = 0; s2 < 8; ++s2) v += rowpart[(size_t)s2 * NROWS + i];
#pragma unroll
  for (int d = 1; d < 64; ++d) v += colpart[(size_t)(d - 1) * NROWS + i];
  float sm = __logf(v);
#pragma unroll
  for (int m = 1; m < 64; m <<= 1) sm += __shfl_xor(sm, m, 64);
  if (tid == 0) {
    atomicAdd(accum, sm);
    __threadfence();
    int prev = atomicAdd(cnt, 1);
    if (prev == (int)gridDim.x - 1) {
      __threadfence();
      float a = __hip_atomic_load(accum, __ATOMIC_RELAXED, __HIP_MEMORY_SCOPE_AGENT);
      out[0] = a / (float)NROWS;
    }
  }
}

extern "C" void kernel_launch(void* const* d_in, const int* in_sizes, int n_in,
                              void* d_out, int out_size, void* d_ws, size_t ws_size,
                              hipStream_t stream) {
  const float* x = (const float*)d_in[0];
  float* out = (float*)d_out;
  // ws layout: xbF 2 MB (fp8, fragment-order) | rowpart 8x64KB |
  //            colpart 63x64KB | accum, cnt
  unsigned char* xbF = (unsigned char*)d_ws;
  float* rowpart = (float*)((char*)d_ws + (size_t)NROWS * DDIM);
  float* colpart = rowpart + (size_t)8 * NROWS;
  float* accum = colpart + (size_t)63 * NROWS;
  int* cnt = (int*)(accum + 1);

  convert_k<<<NROWS / 16, 256, 0, stream>>>(x, xbF, accum, cnt);
  gram_tri_k<<<128 * 8, 512, 0, stream>>>(xbF, rowpart, colpart);
  finalize_k<<<NROWS / 64, 64, 0, stream>>>(rowpart, colpart, accum, cnt, out);
}

// Round 14
// 125.801 us; speedup vs baseline: 1.0635x; 1.0635x over previous
//
#include <hip/hip_runtime.h>
#include <math.h>

// Problem constants (reference: N=16384, D=128, T=0.07)
#define NROWS 16384
#define DDIM  128
constexpr float TEMP = 0.07f;
// Pre-scale trick: x *= sqrt(log2(e)/T) so MFMA emits acc = S*<xi,xj> and
// row_lse = ln(sum exp2(acc)). Diagonal (sim_ii = 1 exactly) masked out of
// the fp8 path, added analytically (2^S) in finalize (R11: absmax 0.0;
// off-diag is ~2.3% of rowsum so fp8 error is damped ~44x).
constexpr float S_EXP = 1.44269504088896f / TEMP;  // 20.6099291

typedef __attribute__((ext_vector_type(4))) float f32x4;

// async 16B global -> LDS (lds dest = wave-uniform base + lane*16)
__device__ __forceinline__ void gload_lds16(const unsigned char* g, unsigned char* l) {
  __builtin_amdgcn_global_load_lds(
      (const __attribute__((address_space(1))) unsigned int*)g,
      (__attribute__((address_space(3))) unsigned int*)l, 16, 0, 0);
}

// Convert + pre-scale to fp8 e4m3 (OCP); zero accum/cnt.
__global__ void convert_k(const float* __restrict__ x, unsigned char* __restrict__ xb,
                          float* __restrict__ accum, int* __restrict__ cnt) {
  const float R = 4.53981419f;  // sqrt(S_EXP); |x*R| <= ~1.3, inside e4m3 range
  int i = (blockIdx.x * blockDim.x + threadIdx.x) * 4;
  float4 v = *(const float4*)(x + i);
  int p = __builtin_amdgcn_cvt_pk_fp8_f32(v.x * R, v.y * R, 0, false);
  p = __builtin_amdgcn_cvt_pk_fp8_f32(v.z * R, v.w * R, p, true);
  *(int*)(xb + i) = p;
  if (blockIdx.x == 0 && threadIdx.x == 0) { *accum = 0.f; *cnt = 0; }
}

// Triangular Gram in fp8. R14: ONE barrier per tile (R11 had two).
// csbuf is double-buffered (2 x 2 KB) so the csbuf-write -> colpart-read
// ordering rides the SAME barrier that publishes the next panel:
//   loop: B (panel[ti&1] staged + csbuf[(ti-1)&1] complete)
//         -> store colpart(ti-1)  [waves 0-1 only; overlaps with below]
//         -> stage(ti+1) into panel[(ti+1)&1]   [full-tile prefetch distance]
//         -> compute(ti) -> q-reduce -> write csbuf[ti&1]
// (R10's mistake was halving barrier WORK while doubling barrier COUNT;
// this halves count at constant prefetch distance. R8 lesson: min-waves 4,
// never 8. Hazards: panel[(ti+1)&1] writers vs compute(ti-1) readers are
// separated by B(ti); csbuf parity reuse separated by B(ti+1).)
// Block (I,s): d-tiles s==0: d=0..8 else 8s+1..8s+8 (union 0..64 once per
// I; d=0 diag-masked, d=0/64 col-skip -- proven R5-R11). Zero contended
// atomics. LDS swizzle (1 B/elem): 16B chunk (col,kc16) at physical chunk
// col*8 + (kc16 ^ ((col>>1)&7)) -> coalesced staging + cheap ds_read_b64.
// 512 thr = 8 waves; wave w: rows h*32 (h=w>>1), cols chalf*64 (chalf=w&1).
__global__ __launch_bounds__(512, 4)
void gram_tri_k(const unsigned char* __restrict__ xb, float* __restrict__ rowpart,
                float* __restrict__ colpart) {
  __shared__ unsigned char panel[2][128 * DDIM];  // 2 x 16 KB
  __shared__ float csbuf[2][512];                 // 2 x 2 KB

  const int tid = threadIdx.x;
  const int w = tid >> 6, lane = tid & 63;
  const int l15 = lane & 15, q = lane >> 4;
  const int I = (int)(blockIdx.x >> 3), s = (int)(blockIdx.x & 7);
  const int rI = I * 128;
  const int h = w >> 1, chalf = w & 1;
  const int dstart = (s == 0) ? 0 : 8 * s + 1;
  const int ntiles = (s == 0) ? 9 : 8;
  const int sc8 = lane >> 3, sk8 = lane & 7;  // staging lane constants

  // A frags: 16x16x32 fp8 A[m=l15][k=q*8+j] -> 8 contiguous bytes/lane
  long af[2][4];
  {
    const unsigned char* gA = xb + (size_t)(rI + h * 32 + l15) * DDIM + q * 8;
#pragma unroll
    for (int rt = 0; rt < 2; ++rt)
#pragma unroll
      for (int kt = 0; kt < 4; ++kt)
        af[rt][kt] = *(const long*)(gA + rt * 16 * DDIM + kt * 32);
  }

  // stage tile 0 into panel[0]
  {
    const unsigned char* gJ = xb + (size_t)(((I + dstart) & 127) * 128) * DDIM;
#pragma unroll
    for (int rr = 0; rr < 2; ++rr) {
      const int col = (w * 2 + rr) * 8 + sc8;
      gload_lds16(gJ + (size_t)col * DDIM + (sk8 ^ ((col >> 1) & 7)) * 16,
                  &panel[0][(w * 2 + rr) * 1024]);
    }
  }

  float rs[2][4];
#pragma unroll
  for (int rt = 0; rt < 2; ++rt)
#pragma unroll
    for (int r = 0; r < 4; ++r) rs[rt][r] = 0.f;

  for (int ti = 0; ti < ntiles; ++ti) {
    const int d = dstart + ti;
    __syncthreads();  // B: panel[ti&1] staged; csbuf[(ti-1)&1] complete
    // deferred colpart store for tile ti-1 (waves 0-1; overlaps stage/compute)
    if (ti > 0) {
      const int pd = d - 1;
      const float* cp = csbuf[(ti - 1) & 1];
      if (pd != 0 && pd != 64 && tid < 128)
        colpart[(size_t)(pd - 1) * NROWS + ((I + pd) & 127) * 128 + tid] =
            cp[tid] + cp[128 + tid] + cp[256 + tid] + cp[384 + tid];
    }
    // stage ti+1 into the OTHER panel (its readers = compute(ti-1), done pre-B)
    if (ti + 1 < ntiles) {
      const unsigned char* gJ =
          xb + (size_t)(((I + dstart + ti + 1) & 127) * 128) * DDIM;
      unsigned char* bn = panel[(ti + 1) & 1];
#pragma unroll
      for (int rr = 0; rr < 2; ++rr) {
        const int col = (w * 2 + rr) * 8 + sc8;
        gload_lds16(gJ + (size_t)col * DDIM + (sk8 ^ ((col >> 1) & 7)) * 16,
                    bn + (w * 2 + rr) * 1024);
      }
    }
    const unsigned char* L = panel[ti & 1];
    const bool dz = (d == 0);

    float cstile[4];
#pragma unroll
    for (int ct = 0; ct < 4; ++ct) {
      const int colb = chalf * 64 + ct * 16 + l15;
      const int swz = (colb >> 1) & 7;
      long bfr[4];
#pragma unroll
      for (int kt = 0; kt < 4; ++kt)
        bfr[kt] = *(const long*)&L[colb * DDIM +
                                   ((((kt << 1) + (q >> 1)) ^ swz) << 4) +
                                   ((q & 1) << 3)];
      float csl = 0.f;
#pragma unroll
      for (int rt = 0; rt < 2; ++rt) {
        f32x4 a = {0.f, 0.f, 0.f, 0.f};
#pragma unroll
        for (int kt = 0; kt < 4; ++kt)
          a = __builtin_amdgcn_mfma_f32_16x16x32_fp8_fp8(af[rt][kt], bfr[kt], a, 0, 0, 0);
        // C/D layout (dtype-independent): col = l15, row = q*4 + r
#pragma unroll
        for (int r = 0; r < 4; ++r) {
          float e = __builtin_amdgcn_exp2f(a[r]);
          if (dz && (h * 32 + rt * 16 + q * 4 + r) == colb) e = 0.f;  // diag
          rs[rt][r] += e;
          csl += e;
        }
      }
      cstile[ct] = csl;
    }
    // col partial: reduce over q (wave's 32 rows), stash per-(h,chalf)
#pragma unroll
    for (int m = 16; m <= 32; m <<= 1)
#pragma unroll
      for (int ct = 0; ct < 4; ++ct)
        cstile[ct] += __shfl_xor(cstile[ct], m, 64);
    if (q == 0) {
#pragma unroll
      for (int ct = 0; ct < 4; ++ct)
        csbuf[ti & 1][h * 128 + chalf * 64 + ct * 16 + l15] = cstile[ct];
    }
    // NO second barrier -- next iteration's B publishes csbuf[ti&1]
  }

  __syncthreads();  // csbuf[(ntiles-1)&1] complete
  // colpart store for the last tile
  {
    const int pd = dstart + ntiles - 1;
    const float* cp = csbuf[(ntiles - 1) & 1];
    if (pd != 0 && pd != 64 && tid < 128)
      colpart[(size_t)(pd - 1) * NROWS + ((I + pd) & 127) * 128 + tid] =
          cp[tid] + cp[128 + tid] + cp[256 + tid] + cp[384 + tid];
  }

  // rows: reduce over the 16 cols (l15) within each wave's 64-col half...
#pragma unroll
  for (int m = 1; m <= 8; m <<= 1)
#pragma unroll
    for (int rt = 0; rt < 2; ++rt)
#pragma unroll
      for (int r = 0; r < 4; ++r)
        rs[rt][r] += __shfl_xor(rs[rt][r], m, 64);
  // ...combine chalf halves via csbuf[0]; chalf=0 is the unique writer.
  __syncthreads();  // tail colpart store done reading csbuf
  if (chalf == 1 && l15 == 0) {
#pragma unroll
    for (int rt = 0; rt < 2; ++rt)
#pragma unroll
      for (int r = 0; r < 4; ++r)
        csbuf[0][h * 32 + rt * 16 + q * 4 + r] = rs[rt][r];
  }
  __syncthreads();
  if (chalf == 0 && l15 == 0) {
#pragma unroll
    for (int rt = 0; rt < 2; ++rt)
#pragma unroll
      for (int r = 0; r < 4; ++r) {
        const int ro = h * 32 + rt * 16 + q * 4 + r;
        rowpart[(size_t)s * NROWS + rI + ro] = rs[rt][r] + csbuf[0][ro];
      }
  }
}

// 256 blocks x 64 threads, 1 row/thread (coalesced): sums 8 rowpart +
// 63 colpart slices, adds analytic diagonal 2^S, logs, wave-reduces.
__global__ void finalize_k(const float* __restrict__ rowpart, const float* __restrict__ colpart,
                           float* __restrict__ accum, int* __restrict__ cnt,
                           float* __restrict__ out) {
  const int tid = threadIdx.x;
  const size_t i = (size_t)blockIdx.x * 64 + tid;
  float v = __builtin_exp2f(S_EXP);  // exact diagonal term (rows unit-norm)
#pragma unroll
  for (int s2 = 0; s2 < 8; ++s2) v += rowpart[(size_t)s2 * NROWS + i];
#pragma unroll
  for (int d = 1; d < 64; ++d) v += colpart[(size_t)(d - 1) * NROWS + i];
  float sm = __logf(v);
#pragma unroll
  for (int m = 1; m < 64; m <<= 1) sm += __shfl_xor(sm, m, 64);
  if (tid == 0) {
    atomicAdd(accum, sm);
    __threadfence();
    int prev = atomicAdd(cnt, 1);
    if (prev == (int)gridDim.x - 1) {
      __threadfence();
      float a = __hip_atomic_load(accum, __ATOMIC_RELAXED, __HIP_MEMORY_SCOPE_AGENT);
      out[0] = a / (float)NROWS;
    }
  }
}

extern "C" void kernel_launch(void* const* d_in, const int* in_sizes, int n_in,
                              void* d_out, int out_size, void* d_ws, size_t ws_size,
                              hipStream_t stream) {
  const float* x = (const float*)d_in[0];
  float* out = (float*)d_out;
  // ws layout: xb 2 MB (fp8) | rowpart 8x64KB | colpart 63x64KB | accum,cnt
  unsigned char* xb = (unsigned char*)d_ws;
  float* rowpart = (float*)((char*)d_ws + (size_t)NROWS * DDIM);
  float* colpart = rowpart + (size_t)8 * NROWS;
  float* accum = colpart + (size_t)63 * NROWS;
  int* cnt = (int*)(accum + 1);

  convert_k<<<NROWS * DDIM / (256 * 4), 256, 0, stream>>>(x, xb, accum, cnt);
  gram_tri_k<<<128 * 8, 512, 0, stream>>>(xb, rowpart, colpart);
  finalize_k<<<NROWS / 64, 64, 0, stream>>>(rowpart, colpart, accum, cnt, out);
}